// Round 1
// baseline (215.968 us; speedup 1.0000x reference)
//
#include <hip/hip_runtime.h>
#include <hip/hip_bf16.h>
#include <stdint.h>

typedef __hip_bfloat16 bf16;
typedef __attribute__((ext_vector_type(8))) short bf16x8;   // 8 bf16 = 4 VGPRs (MFMA A/B frag)
typedef __attribute__((ext_vector_type(4))) float f32x4;    // MFMA C/D frag

#define B_  2
#define L_  2048
#define D_  1024
#define H_  16
#define HD_ 64
#define BH_ 32

#define DEV static __device__ __forceinline__

DEV short f2bf(float f) {
    bf16 h = __float2bfloat16(f);
    return __builtin_bit_cast(short, h);
}

DEV f32x4 mfma16(bf16x8 a, bf16x8 b, f32x4 c) {
    return __builtin_amdgcn_mfma_f32_16x16x32_bf16(a, b, c, 0, 0, 0);
}

// async global->LDS, 16B per lane; lds ptr must be wave-uniform (HW adds lane*16)
DEV void async_ld16(const void* g, void* lds_uniform) {
    __builtin_amdgcn_global_load_lds((const __attribute__((address_space(1))) void*)g,
                                     (__attribute__((address_space(3))) void*)lds_uniform,
                                     16, 0, 0);
}

// XOR-swizzled element offset inside a [rows][64] bf16 tile (128B rows).
// 16B block = (row*8 + col/8) ^ (row&7)  -> spreads column reads across 8 slots.
DEV int swz(int row, int col) {
    int blk = (row << 3) + (col >> 3);
    blk ^= (row & 7);
    return (blk << 3) + (col & 7);
}

// ---------------------------------------------------------------- cast x -> bf16
__global__ __launch_bounds__(256) void k_cast_x(const float* __restrict__ x,
                                                bf16* __restrict__ xb, int n8) {
    int i = blockIdx.x * 256 + threadIdx.x;
    if (i >= n8) return;
    const float4* src = (const float4*)x + (size_t)i * 2;
    float4 a = src[0], b = src[1];
    bf16x8 v;
    v[0]=f2bf(a.x); v[1]=f2bf(a.y); v[2]=f2bf(a.z); v[3]=f2bf(a.w);
    v[4]=f2bf(b.x); v[5]=f2bf(b.y); v[6]=f2bf(b.z); v[7]=f2bf(b.w);
    *(bf16x8*)(xb + (size_t)i * 8) = v;
}

// ------------------------------------------- cast + transpose weights -> WT[n][k] bf16
__global__ __launch_bounds__(256) void k_cast_wT(const float* __restrict__ W0, const float* __restrict__ W1,
                                                 const float* __restrict__ W2, const float* __restrict__ W3,
                                                 bf16* __restrict__ WT) {
    const float* W = (blockIdx.z == 0) ? W0 : (blockIdx.z == 1) ? W1 : (blockIdx.z == 2) ? W2 : W3;
    __shared__ float tile[64][65];
    const int r0 = blockIdx.y * 64, c0 = blockIdx.x * 64;
    const int tx = threadIdx.x & 63, ty = threadIdx.x >> 6;
    #pragma unroll
    for (int i = 0; i < 16; ++i) {
        int r = ty + i * 4;
        tile[r][tx] = W[(size_t)(r0 + r) * D_ + c0 + tx];
    }
    __syncthreads();
    bf16* out = WT + (size_t)blockIdx.z * D_ * D_;
    #pragma unroll
    for (int i = 0; i < 16; ++i) {
        int n = ty + i * 4;
        out[(size_t)(c0 + n) * D_ + r0 + tx] = __float2bfloat16(tile[tx][n]);
    }
}

// ---------------------------------------------------------------- GEMM 128x128, BK=64
// C[M,N] = A[M,1024] * BT[N,1024]^T.  MODE 0: scatter bf16 into QKV regions. MODE 1: f32 out.
template <int MODE>
__global__ __launch_bounds__(256) void k_gemm(const bf16* __restrict__ A, const bf16* __restrict__ BT,
                                              void* __restrict__ C) {
    __shared__ __align__(16) bf16 As[128 * 64];
    __shared__ __align__(16) bf16 Bs[128 * 64];
    const int t = threadIdx.x;
    const int w = t >> 6, lane = t & 63;
    const int lr = lane & 15, lg = lane >> 4;
    const int wr = (w >> 1) * 64, wc = (w & 1) * 64;
    const size_t am0 = (size_t)blockIdx.y * 128;
    const size_t bn0 = (size_t)blockIdx.x * 128;

    f32x4 acc[4][4] = {};

    for (int kt = 0; kt < 1024 / 64; ++kt) {
        const int k0 = kt * 64;
        if (kt) __syncthreads();
        // stage both tiles (each 128x64 bf16 = 1024 x 16B blocks); swizzled global source,
        // linear LDS dest (rule #21: inverse-permute source, swizzle on read)
        #pragma unroll
        for (int c = 0; c < 4; ++c) {
            int phys = c * 256 + t;
            int lb = phys ^ ((phys >> 3) & 7);
            int row = lb >> 3, cb = lb & 7;
            int ldsoff = (c * 256 + w * 64) * 8;
            async_ld16(A  + (am0 + row) * 1024 + k0 + cb * 8, (void*)(As + ldsoff));
            async_ld16(BT + (bn0 + row) * 1024 + k0 + cb * 8, (void*)(Bs + ldsoff));
        }
        __syncthreads();
        bf16x8 af[4][2], bfv[4][2];
        #pragma unroll
        for (int mi = 0; mi < 4; ++mi)
            #pragma unroll
            for (int ks = 0; ks < 2; ++ks)
                af[mi][ks] = *(const bf16x8*)(As + swz(wr + mi * 16 + lr, ks * 32 + lg * 8));
        #pragma unroll
        for (int ni = 0; ni < 4; ++ni)
            #pragma unroll
            for (int ks = 0; ks < 2; ++ks)
                bfv[ni][ks] = *(const bf16x8*)(Bs + swz(wc + ni * 16 + lr, ks * 32 + lg * 8));
        #pragma unroll
        for (int mi = 0; mi < 4; ++mi)
            #pragma unroll
            for (int ni = 0; ni < 4; ++ni) {
                acc[mi][ni] = mfma16(af[mi][0], bfv[ni][0], acc[mi][ni]);
                acc[mi][ni] = mfma16(af[mi][1], bfv[ni][1], acc[mi][ni]);
            }
    }

    #pragma unroll
    for (int mi = 0; mi < 4; ++mi)
        #pragma unroll
        for (int ni = 0; ni < 4; ++ni)
            #pragma unroll
            for (int j = 0; j < 4; ++j) {
                size_t gm = am0 + wr + mi * 16 + lg * 4 + j;
                size_t gn = bn0 + wc + ni * 16 + lr;
                float v = acc[mi][ni][j];
                if (MODE == 0) {
                    int which = (int)(gn >> 10);
                    int h = (int)((gn >> 6) & 15);
                    int d = (int)(gn & 63);
                    int bb = (int)(gm >> 11);
                    int l = (int)(gm & 2047);
                    bf16* dst = (bf16*)C + (size_t)which * ((size_t)BH_ * L_ * HD_);
                    dst[((size_t)(bb * H_ + h) * L_ + l) * HD_ + d] = __float2bfloat16(v);
                } else {
                    ((float*)C)[gm * 1024 + gn] = v;
                }
            }
}

// ---------------------------------------------------------------- V transpose per head
// Vb [bh][L][64] -> VTb [bh][64][L]
__global__ __launch_bounds__(256) void k_transpose_v(const bf16* __restrict__ Vb, bf16* __restrict__ VTb) {
    __shared__ __align__(16) short tile[64][80];
    const int bh = blockIdx.y;
    const int l0 = blockIdx.x * 64;
    const int t = threadIdx.x;
    const int rr = t >> 2, cc = (t & 3) * 16;
    const short* src = (const short*)(Vb + ((size_t)bh * L_ + l0 + rr) * HD_ + cc);
    *(bf16x8*)&tile[rr][cc]     = *(const bf16x8*)src;
    *(bf16x8*)&tile[rr][cc + 8] = *(const bf16x8*)(src + 8);
    __syncthreads();
    bf16x8 v0, v1;
    #pragma unroll
    for (int i = 0; i < 8; ++i) v0[i] = tile[cc + i][rr];
    #pragma unroll
    for (int i = 0; i < 8; ++i) v1[i] = tile[cc + 8 + i][rr];
    short* dst = (short*)(VTb + ((size_t)bh * HD_ + rr) * L_ + l0 + cc);
    *(bf16x8*)dst       = v0;
    *(bf16x8*)(dst + 8) = v1;
}

// ---------------------------------------------------------------- fused attention
// grid (L/64, H). Each block: one 64-row Q tile, BOTH batches (PE fetched once).
__global__ __launch_bounds__(256) void k_attn(const bf16* __restrict__ Qb, const bf16* __restrict__ Kb,
                                              const bf16* __restrict__ VTb, const float* __restrict__ PE,
                                              bf16* __restrict__ Ob) {
    __shared__ __align__(16) bf16 Ks[2][64 * 64];
    __shared__ __align__(16) bf16 Vs[2][64 * 64];
    __shared__ __align__(16) bf16 Ps[2][64 * 64];
    const int qt = blockIdx.x, h = blockIdx.y;
    const int q0 = qt * 64;
    const int t = threadIdx.x, w = t >> 6, lane = t & 63;
    const int lr = lane & 15, lg = lane >> 4;

    // Q fragments held in registers for the whole kernel (Q-hoist)
    bf16x8 qf[2][2];
    #pragma unroll
    for (int bi = 0; bi < 2; ++bi) {
        const bf16* qsrc = Qb + (((size_t)(bi * H_ + h)) * L_ + q0 + w * 16 + lr) * HD_ + lg * 8;
        qf[bi][0] = *(const bf16x8*)qsrc;
        qf[bi][1] = *(const bf16x8*)(qsrc + 32);
    }

    f32x4 o[2][4] = {};
    float mrun[2][4], lrun[2][4];
    #pragma unroll
    for (int bi = 0; bi < 2; ++bi)
        #pragma unroll
        for (int j = 0; j < 4; ++j) { mrun[bi][j] = -1e30f; lrun[bi][j] = 0.f; }

    const float* peb = PE + ((size_t)h * L_ + q0 + w * 16 + lg * 4) * L_ + lr;

    for (int it = 0; it < L_ / 64; ++it) {
        const int k0 = it * 64;
        if (it) __syncthreads();
        #pragma unroll
        for (int bi = 0; bi < 2; ++bi) {
            const bf16* kbase = Kb + (((size_t)(bi * H_ + h)) * L_ + k0) * HD_;
            const bf16* vbase = VTb + ((size_t)(bi * H_ + h)) * HD_ * L_ + k0;
            #pragma unroll
            for (int c = 0; c < 2; ++c) {
                int phys = c * 256 + t;
                int lb = phys ^ ((phys >> 3) & 7);
                int row = lb >> 3, cb = lb & 7;
                int ldsoff = (c * 256 + w * 64) * 8;
                async_ld16(kbase + (size_t)row * HD_ + cb * 8, (void*)(Ks[bi] + ldsoff));
                async_ld16(vbase + (size_t)row * L_  + cb * 8, (void*)(Vs[bi] + ldsoff));
            }
        }
        // positional bias: fetched once, used for both batches
        float pe[4][4];
        #pragma unroll
        for (int jj = 0; jj < 4; ++jj)
            #pragma unroll
            for (int ni = 0; ni < 4; ++ni)
                pe[jj][ni] = peb[(size_t)jj * L_ + k0 + ni * 16];
        __syncthreads();

        #pragma unroll
        for (int bi = 0; bi < 2; ++bi) {
            // S = Q K^T / 8 + PE   (per wave: 16 q-rows x 64 kv)
            f32x4 s[4];
            #pragma unroll
            for (int ni = 0; ni < 4; ++ni) {
                f32x4 z = {0.f, 0.f, 0.f, 0.f};
                z = mfma16(qf[bi][0], *(const bf16x8*)(Ks[bi] + swz(ni * 16 + lr, lg * 8)), z);
                z = mfma16(qf[bi][1], *(const bf16x8*)(Ks[bi] + swz(ni * 16 + lr, 32 + lg * 8)), z);
                s[ni] = z;
            }
            // online softmax per q-row (row = lg*4 + jj, 128 kv values live in 16 lanes x 4 frags)
            #pragma unroll
            for (int jj = 0; jj < 4; ++jj) {
                float vm = -1e30f;
                #pragma unroll
                for (int ni = 0; ni < 4; ++ni) {
                    float val = s[ni][jj] * 0.125f + pe[jj][ni];
                    s[ni][jj] = val;
                    vm = fmaxf(vm, val);
                }
                #pragma unroll
                for (int off = 1; off < 16; off <<= 1) vm = fmaxf(vm, __shfl_xor(vm, off, 64));
                float mnew = fmaxf(mrun[bi][jj], vm);
                float scl = __expf(mrun[bi][jj] - mnew);
                mrun[bi][jj] = mnew;
                float rs = 0.f;
                #pragma unroll
                for (int ni = 0; ni < 4; ++ni) {
                    float p = __expf(s[ni][jj] - mnew);
                    rs += p;
                    Ps[bi][swz(w * 16 + lg * 4 + jj, ni * 16 + lr)] = __float2bfloat16(p);
                }
                #pragma unroll
                for (int off = 1; off < 16; off <<= 1) rs += __shfl_xor(rs, off, 64);
                lrun[bi][jj] = lrun[bi][jj] * scl + rs;
                o[bi][0][jj] *= scl; o[bi][1][jj] *= scl;
                o[bi][2][jj] *= scl; o[bi][3][jj] *= scl;
            }
            // O += P V  (P rows are this wave's own -> no barrier needed, wave-order LDS)
            #pragma unroll
            for (int ks = 0; ks < 2; ++ks) {
                bf16x8 pa = *(const bf16x8*)(Ps[bi] + swz(w * 16 + lr, ks * 32 + lg * 8));
                #pragma unroll
                for (int di = 0; di < 4; ++di) {
                    bf16x8 vb = *(const bf16x8*)(Vs[bi] + swz(di * 16 + lr, ks * 32 + lg * 8));
                    o[bi][di] = mfma16(pa, vb, o[bi][di]);
                }
            }
        }
    }
    // normalize + store to Ob [B*L][1024] at column h*64
    #pragma unroll
    for (int bi = 0; bi < 2; ++bi)
        #pragma unroll
        for (int di = 0; di < 4; ++di)
            #pragma unroll
            for (int jj = 0; jj < 4; ++jj) {
                float v = o[bi][di][jj] / lrun[bi][jj];
                size_t gq = q0 + w * 16 + lg * 4 + jj;
                Ob[((size_t)bi * L_ + gq) * D_ + h * HD_ + di * 16 + lr] = __float2bfloat16(v);
            }
}

// ---------------------------------------------------------------- launch
extern "C" void kernel_launch(void* const* d_in, const int* in_sizes, int n_in,
                              void* d_out, int out_size, void* d_ws, size_t ws_size,
                              hipStream_t stream) {
    const float* x  = (const float*)d_in[0];
    const float* pe = (const float*)d_in[1];
    const float* Wq = (const float*)d_in[2];
    const float* Wk = (const float*)d_in[3];
    const float* Wv = (const float*)d_in[4];
    const float* Wo = (const float*)d_in[5];
    float* out = (float*)d_out;

    const size_t MD = (size_t)4096 * 1024;       // 4 Mi elements
    const size_t HS = (size_t)BH_ * L_ * HD_;    // 4 Mi elements per head-major tensor

    bf16* Xb  = (bf16*)d_ws;        // x in bf16            [4096][1024]
    bf16* WT  = Xb + MD;            // WqT|WkT|WvT|WoT      [4096][1024]
    bf16* Qb  = WT + MD;            // [bh][L][64]
    bf16* Kb  = Qb + HS;
    bf16* Vb  = Kb + HS;
    bf16* VTb = Vb + HS;            // [bh][64][L]
    bf16* Ob  = VTb + HS;           // attention out        [4096][1024]

    k_cast_x<<<2048, 256, 0, stream>>>(x, Xb, 4096 * 1024 / 8);
    k_cast_wT<<<dim3(16, 16, 4), 256, 0, stream>>>(Wq, Wk, Wv, Wo, WT);
    k_gemm<0><<<dim3(24, 32), 256, 0, stream>>>(Xb, WT, (void*)Qb);          // QKV, N=3072
    k_transpose_v<<<dim3(32, 32), 256, 0, stream>>>(Vb, VTb);
    k_attn<<<dim3(32, 16), 256, 0, stream>>>(Qb, Kb, VTb, pe, Ob);
    k_gemm<1><<<dim3(8, 32), 256, 0, stream>>>(Ob, WT + (size_t)3072 * 1024, (void*)out); // out-proj
}